// Round 12
// baseline (855.781 us; speedup 1.0000x reference)
//
#include <hip/hip_runtime.h>
#include <hip/hip_bf16.h>

#define NPTS 200000
#define INC  64
#define OUTC 128
#define KTAP 27
#define EPSV 1e-5f
#define BM   128
#define NSHADOW 32

typedef __attribute__((ext_vector_type(8))) short bf16x8;
typedef __attribute__((ext_vector_type(4))) float f32x4;

__device__ __forceinline__ unsigned short f2bf(float f) {
  unsigned int u = __float_as_uint(f);
  return (unsigned short)((u + 0x7FFFu + ((u >> 16) & 1u)) >> 16);
}

// Fragment-packed bf16 weight image, 16KB/tap (R9-verified layout):
// chunk id=(ct*2+kk)*64+lane holds w[kk*32+(lane>>4)*8+j][ct*16+(lane&15)], j=0..7
__global__ void prep_wfrag(const float* __restrict__ w, unsigned char* __restrict__ img) {
  int tap = blockIdx.x;
  const float* wk = w + tap * (INC * OUTC);
  for (int id = threadIdx.x; id < 1024; id += blockDim.x) {
    int lane = id & 63;
    int ck   = id >> 6;
    int ct   = ck >> 1, kk = ck & 1;
    int c    = ct * 16 + (lane & 15);
    int k0   = kk * 32 + (lane >> 4) * 8;
    ushort4 lo, hi;
    lo.x = f2bf(wk[(k0+0)*OUTC + c]); lo.y = f2bf(wk[(k0+1)*OUTC + c]);
    lo.z = f2bf(wk[(k0+2)*OUTC + c]); lo.w = f2bf(wk[(k0+3)*OUTC + c]);
    hi.x = f2bf(wk[(k0+4)*OUTC + c]); hi.y = f2bf(wk[(k0+5)*OUTC + c]);
    hi.z = f2bf(wk[(k0+6)*OUTC + c]); hi.w = f2bf(wk[(k0+7)*OUTC + c]);
    unsigned char* d = img + (size_t)tap * 16384 + (size_t)id * 16;
    *(ushort4*)d       = lo;
    *(ushort4*)(d + 8) = hi;
  }
}

// feats fp32 (N x 64) -> bf16 rows of 128B.
__global__ __launch_bounds__(256) void prep_feats(const float* __restrict__ f,
                                                  unsigned short* __restrict__ o) {
  size_t i = (size_t)blockIdx.x * 256 + threadIdx.x;
  float4 a = ((const float4*)f)[i * 2];
  float4 b = ((const float4*)f)[i * 2 + 1];
  ushort4 ha = make_ushort4(f2bf(a.x), f2bf(a.y), f2bf(a.z), f2bf(a.w));
  ushort4 hb = make_ushort4(f2bf(b.x), f2bf(b.y), f2bf(b.z), f2bf(b.w));
  ((ushort4*)o)[i * 2]     = ha;
  ((ushort4*)o)[i * 2 + 1] = hb;
}

__global__ __launch_bounds__(512, 8) void conv_main(
    const unsigned short* __restrict__ fbf,   // NPTS+1 rows; row NPTS is zeros
    const int*   __restrict__ nmap,
    const unsigned char* __restrict__ wimg,
    float* __restrict__ out,
    float* __restrict__ shadow)
{
  __shared__ __align__(16) unsigned char ldsB[2][16384];   // 32KB -> 4 blocks/CU

  const int t    = threadIdx.x;
  const int lane = t & 63;
  const int w    = t >> 6;       // 0..7
  const int cg   = w & 1;        // col group (64 cols)
  const int rg   = w >> 1;       // row group (32 rows, wave-exclusive)
  const int n0   = blockIdx.x * BM;
  const int l15  = lane & 15;
  const int lg   = lane >> 4;

  f32x4 zv = {0.f, 0.f, 0.f, 0.f};
  f32x4 acc[2][4];
  #pragma unroll
  for (int i = 0; i < 2; ++i)
    #pragma unroll
    for (int j = 0; j < 4; ++j) acc[i][j] = zv;

  const int nr0 = n0 + rg * 32 + l15;
  const int nr1 = nr0 + 16;
  const bool ok0 = nr0 < NPTS, ok1 = nr1 < NPTS;
  const int nc0 = ok0 ? nr0 : (NPTS - 1);
  const int nc1 = ok1 ? nr1 : (NPTS - 1);

  const unsigned char* fbp = (const unsigned char*)fbf;
  // invalid (g<0) or tail row -> zero row NPTS: no masking anywhere
  auto gp = [&](int g, bool ok) -> const unsigned char* {
    int gc = (g >= 0) ? g : NPTS;
    gc = ok ? gc : NPTS;
    return fbp + (size_t)gc * 128 + lg * 16;
  };

  // stage tap k into slot (16KB linear glds copy)
  auto stage = [&](int k, int slot) {
    const unsigned char* src = wimg + (size_t)k * 16384 + (size_t)t * 16;
    __builtin_amdgcn_global_load_lds(
        (const __attribute__((address_space(1))) void*)src,
        (__attribute__((address_space(3))) void*)(&ldsB[slot][t * 16]), 16, 0, 0);
    __builtin_amdgcn_global_load_lds(
        (const __attribute__((address_space(1))) void*)(src + 8192),
        (__attribute__((address_space(3))) void*)(&ldsB[slot][t * 16 + 8192]), 16, 0, 0);
  };

  const unsigned bb = (unsigned)(cg * 8192 + lane * 16);

  // one tap, no syncs inside: A(kn+2) gathers + idx(kn+4) + 16 MFMAs
  auto do_tap = [&](int kn, int slot,
                    bf16x8& A0, bf16x8& A1, bf16x8& A2, bf16x8& A3,
                    int& Q0, int& Q1, bool doG) {
    const unsigned char* bufR = ldsB[slot];
    bf16x8 nA0, nA1, nA2, nA3;
    if (doG) {
      const unsigned char* p0 = gp(Q0, ok0);
      const unsigned char* p1 = gp(Q1, ok1);
      nA0 = *(const bf16x8*)p0; nA1 = *(const bf16x8*)(p0 + 64);
      nA2 = *(const bf16x8*)p1; nA3 = *(const bf16x8*)(p1 + 64);
    }
    int kq = (kn + 4 < KTAP) ? (kn + 4) : (KTAP - 1);
    int nQ0 = nmap[(size_t)kq * NPTS + nc0];
    int nQ1 = nmap[(size_t)kq * NPTS + nc1];
    #pragma unroll
    for (int kk = 0; kk < 2; ++kk) {
      bf16x8 b0 = *(const bf16x8*)(bufR + bb + kk * 1024 + 0 * 2048);
      bf16x8 b1 = *(const bf16x8*)(bufR + bb + kk * 1024 + 1 * 2048);
      bf16x8 b2 = *(const bf16x8*)(bufR + bb + kk * 1024 + 2 * 2048);
      bf16x8 b3 = *(const bf16x8*)(bufR + bb + kk * 1024 + 3 * 2048);
      bf16x8 a0 = kk ? A1 : A0;
      bf16x8 a1 = kk ? A3 : A2;
      acc[0][0] = __builtin_amdgcn_mfma_f32_16x16x32_bf16(a0, b0, acc[0][0], 0, 0, 0);
      acc[0][1] = __builtin_amdgcn_mfma_f32_16x16x32_bf16(a0, b1, acc[0][1], 0, 0, 0);
      acc[0][2] = __builtin_amdgcn_mfma_f32_16x16x32_bf16(a0, b2, acc[0][2], 0, 0, 0);
      acc[0][3] = __builtin_amdgcn_mfma_f32_16x16x32_bf16(a0, b3, acc[0][3], 0, 0, 0);
      acc[1][0] = __builtin_amdgcn_mfma_f32_16x16x32_bf16(a1, b0, acc[1][0], 0, 0, 0);
      acc[1][1] = __builtin_amdgcn_mfma_f32_16x16x32_bf16(a1, b1, acc[1][1], 0, 0, 0);
      acc[1][2] = __builtin_amdgcn_mfma_f32_16x16x32_bf16(a1, b2, acc[1][2], 0, 0, 0);
      acc[1][3] = __builtin_amdgcn_mfma_f32_16x16x32_bf16(a1, b3, acc[1][3], 0, 0, 0);
    }
    if (doG) { A0 = nA0; A1 = nA1; A2 = nA2; A3 = nA3; }
    Q0 = nQ0; Q1 = nQ1;
  };

  // ---- prologue: idx taps 0..3; A(0), A(1); stage tap 0 ----
  int j00 = nmap[nc0],                     j01 = nmap[nc1];
  int j10 = nmap[(size_t)NPTS + nc0],      j11 = nmap[(size_t)NPTS + nc1];
  int q00 = nmap[(size_t)2 * NPTS + nc0],  q01 = nmap[(size_t)2 * NPTS + nc1];
  int q10 = nmap[(size_t)3 * NPTS + nc0],  q11 = nmap[(size_t)3 * NPTS + nc1];

  bf16x8 aC0, aC1, aC2, aC3;   // even taps
  bf16x8 aN0, aN1, aN2, aN3;   // odd taps
  { const unsigned char* p = gp(j00, ok0); aC0 = *(const bf16x8*)p; aC1 = *(const bf16x8*)(p + 64); }
  { const unsigned char* p = gp(j01, ok1); aC2 = *(const bf16x8*)p; aC3 = *(const bf16x8*)(p + 64); }
  { const unsigned char* p = gp(j10, ok0); aN0 = *(const bf16x8*)p; aN1 = *(const bf16x8*)(p + 64); }
  { const unsigned char* p = gp(j11, ok1); aN2 = *(const bf16x8*)p; aN3 = *(const bf16x8*)(p + 64); }

  stage(0, 0);
  __syncthreads();   // tap-0 B staged (full drain; correct by construction)

  // ---- main loop: 1 barrier per tap; stage(kn+1) issued before compute ----
  #pragma unroll 1
  for (int kn = 0; kn < KTAP - 1; kn += 2) {
    stage(kn + 1, 1);
    do_tap(kn, 0, aC0, aC1, aC2, aC3, q00, q01, true);
    __syncthreads();                      // glds(kn+1) done; readers done slot0
    if (kn + 2 < KTAP) stage(kn + 2, 0);
    do_tap(kn + 1, 1, aN0, aN1, aN2, aN3, q10, q11, true);
    __syncthreads();                      // glds(kn+2) done; readers done slot1
  }
  do_tap(KTAP - 1, 0, aC0, aC1, aC2, aC3, q00, q01, false);   // tap 26 (even)

  // ---- epilogue: guarded stores + wave-reduced sums -> 32-shadow atomics ----
  float* mysh = shadow + (blockIdx.x & (NSHADOW - 1)) * 256;
  #pragma unroll
  for (int nf = 0; nf < 4; ++nf) {
    int c = cg * 64 + nf * 16 + l15;
    float s = 0.f, s2 = 0.f;
    #pragma unroll
    for (int rt = 0; rt < 2; ++rt) {
      #pragma unroll
      for (int r = 0; r < 4; ++r) {
        float v = acc[rt][nf][r];
        int n = n0 + rg * 32 + rt * 16 + lg * 4 + r;
        if (n < NPTS) {
          s += v; s2 += v * v;
          out[(size_t)n * OUTC + c] = v;
        }
      }
    }
    s  += __shfl_xor(s, 16);  s  += __shfl_xor(s, 32);
    s2 += __shfl_xor(s2, 16); s2 += __shfl_xor(s2, 32);
    if (lane < 16) {
      atomicAdd(&mysh[c], s);
      atomicAdd(&mysh[128 + c], s2);
    }
  }
}

__global__ void finalize_stats(const float* __restrict__ shadow,
                               const float* __restrict__ gamma,
                               const float* __restrict__ beta,
                               float* __restrict__ scale,
                               float* __restrict__ shift) {
  __shared__ float accs[256];
  int t = threadIdx.x;
  float s = 0.f;
  for (int b = 0; b < NSHADOW; ++b) s += shadow[b * 256 + t];
  accs[t] = s;
  __syncthreads();
  if (t < OUTC) {
    float mean = accs[t] * (1.0f / (float)NPTS);
    float var  = accs[128 + t] * (1.0f / (float)NPTS) - mean * mean;
    var = fmaxf(var, 0.f);
    float sc = gamma[t] * rsqrtf(var + EPSV);
    scale[t] = sc;
    shift[t] = beta[t] - mean * sc;
  }
}

__global__ __launch_bounds__(256) void norm_relu(float* __restrict__ out,
                                                 const float* __restrict__ scale,
                                                 const float* __restrict__ shift) {
  __shared__ float s_sc[OUTC], s_sh[OUTC];
  if (threadIdx.x < OUTC) {
    s_sc[threadIdx.x] = scale[threadIdx.x];
    s_sh[threadIdx.x] = shift[threadIdx.x];
  }
  __syncthreads();
  const long total = (long)NPTS * OUTC / 4;
  for (long i = (long)blockIdx.x * blockDim.x + threadIdx.x; i < total;
       i += (long)gridDim.x * blockDim.x) {
    float4 v = ((float4*)out)[i];
    int cb = (int)(i & 31) * 4;
    v.x = fmaxf(v.x * s_sc[cb + 0] + s_sh[cb + 0], 0.f);
    v.y = fmaxf(v.y * s_sc[cb + 1] + s_sh[cb + 1], 0.f);
    v.z = fmaxf(v.z * s_sc[cb + 2] + s_sh[cb + 2], 0.f);
    v.w = fmaxf(v.w * s_sc[cb + 3] + s_sh[cb + 3], 0.f);
    ((float4*)out)[i] = v;
  }
}

extern "C" void kernel_launch(void* const* d_in, const int* in_sizes, int n_in,
                              void* d_out, int out_size, void* d_ws, size_t ws_size,
                              hipStream_t stream) {
  (void)in_sizes; (void)n_in; (void)out_size; (void)ws_size;
  const float* feats  = (const float*)d_in[0];
  const float* weight = (const float*)d_in[1];
  const float* gamma  = (const float*)d_in[2];
  const float* beta   = (const float*)d_in[3];
  const int*   nmap   = (const int*)d_in[4];
  float* out = (float*)d_out;

  unsigned char* ws = (unsigned char*)d_ws;
  const size_t FBF_BYTES  = (size_t)(NPTS + 1) * 128;  // 25,600,128 (+ zero row)
  const size_t WIMG_BYTES = (size_t)KTAP * 16384;      // 442,368
  unsigned short* fbf = (unsigned short*)ws;
  unsigned char* wimg = ws + FBF_BYTES;
  float* shadow = (float*)(ws + FBF_BYTES + WIMG_BYTES);  // 32*256
  float* scale  = shadow + NSHADOW * 256;
  float* shift  = scale + 128;

  hipMemsetAsync(shadow, 0, NSHADOW * 256 * sizeof(float), stream);
  hipMemsetAsync(fbf + (size_t)NPTS * 64, 0, 128, stream);   // zero row
  prep_wfrag<<<KTAP, 256, 0, stream>>>(weight, wimg);
  prep_feats<<<6250, 256, 0, stream>>>(feats, fbf);
  int grid = (NPTS + BM - 1) / BM;  // 1563
  conv_main<<<grid, 512, 0, stream>>>(fbf, nmap, wimg, out, shadow);
  finalize_stats<<<1, 256, 0, stream>>>(shadow, gamma, beta, scale, shift);
  norm_relu<<<4096, 256, 0, stream>>>(out, scale, shift);
}

// Round 16
// 183.203 us; speedup vs baseline: 4.6712x; 4.6712x over previous
//
#include <hip/hip_runtime.h>
#include <hip/hip_bf16.h>

#define NPTS 200000
#define INC  64
#define OUTC 128
#define KTAP 27
#define EPSV 1e-5f
#define BM   128
#define NSHADOW 32

typedef __attribute__((ext_vector_type(8))) short bf16x8;
typedef __attribute__((ext_vector_type(4))) float f32x4;

__device__ __forceinline__ unsigned short f2bf(float f) {
  unsigned int u = __float_as_uint(f);
  return (unsigned short)((u + 0x7FFFu + ((u >> 16) & 1u)) >> 16);
}

// Fragment-packed bf16 weight image, 16KB/tap (R9-verified layout):
// chunk id=(ct*2+kk)*64+lane holds w[kk*32+(lane>>4)*8+j][ct*16+(lane&15)], j=0..7
__global__ void prep_wfrag(const float* __restrict__ w, unsigned char* __restrict__ img) {
  int tap = blockIdx.x;
  const float* wk = w + tap * (INC * OUTC);
  for (int id = threadIdx.x; id < 1024; id += blockDim.x) {
    int lane = id & 63;
    int ck   = id >> 6;
    int ct   = ck >> 1, kk = ck & 1;
    int c    = ct * 16 + (lane & 15);
    int k0   = kk * 32 + (lane >> 4) * 8;
    ushort4 lo, hi;
    lo.x = f2bf(wk[(k0+0)*OUTC + c]); lo.y = f2bf(wk[(k0+1)*OUTC + c]);
    lo.z = f2bf(wk[(k0+2)*OUTC + c]); lo.w = f2bf(wk[(k0+3)*OUTC + c]);
    hi.x = f2bf(wk[(k0+4)*OUTC + c]); hi.y = f2bf(wk[(k0+5)*OUTC + c]);
    hi.z = f2bf(wk[(k0+6)*OUTC + c]); hi.w = f2bf(wk[(k0+7)*OUTC + c]);
    unsigned char* d = img + (size_t)tap * 16384 + (size_t)id * 16;
    *(ushort4*)d       = lo;
    *(ushort4*)(d + 8) = hi;
  }
}

// feats fp32 (N x 64) -> bf16 rows of 128B.
__global__ __launch_bounds__(256) void prep_feats(const float* __restrict__ f,
                                                  unsigned short* __restrict__ o) {
  size_t i = (size_t)blockIdx.x * 256 + threadIdx.x;
  float4 a = ((const float4*)f)[i * 2];
  float4 b = ((const float4*)f)[i * 2 + 1];
  ushort4 ha = make_ushort4(f2bf(a.x), f2bf(a.y), f2bf(a.z), f2bf(a.w));
  ushort4 hb = make_ushort4(f2bf(b.x), f2bf(b.y), f2bf(b.z), f2bf(b.w));
  ((ushort4*)o)[i * 2]     = ha;
  ((ushort4*)o)[i * 2 + 1] = hb;
}

__global__ __launch_bounds__(512, 4) void conv_main(
    const unsigned short* __restrict__ fbf,   // NPTS+1 rows; row NPTS is zeros
    const int*   __restrict__ nmap,
    const unsigned char* __restrict__ wimg,
    float* __restrict__ out,
    float* __restrict__ shadow)
{
  __shared__ __align__(16) unsigned char ldsB[2][16384];   // 32KB

  const int t    = threadIdx.x;
  const int lane = t & 63;
  const int w    = t >> 6;       // 0..7
  const int cg   = w & 1;        // col group (64 cols)
  const int rg   = w >> 1;       // row group (32 rows, wave-exclusive)
  const int n0   = blockIdx.x * BM;
  const int l15  = lane & 15;
  const int lg   = lane >> 4;

  f32x4 zv = {0.f, 0.f, 0.f, 0.f};
  f32x4 acc[2][4];
  #pragma unroll
  for (int i = 0; i < 2; ++i)
    #pragma unroll
    for (int j = 0; j < 4; ++j) acc[i][j] = zv;

  const int nr0 = n0 + rg * 32 + l15;
  const int nr1 = nr0 + 16;
  const bool ok0 = nr0 < NPTS, ok1 = nr1 < NPTS;
  const int nc0 = ok0 ? nr0 : (NPTS - 1);
  const int nc1 = ok1 ? nr1 : (NPTS - 1);

  const unsigned char* fbp = (const unsigned char*)fbf;
  // invalid (g<0) or tail row -> zero row NPTS: no masking anywhere
  auto gp = [&](int g, bool ok) -> const unsigned char* {
    int gc = (g >= 0) ? g : NPTS;
    gc = ok ? gc : NPTS;
    return fbp + (size_t)gc * 128 + lg * 16;
  };

  // stage tap k into slot (16KB linear glds copy)
  auto stage = [&](int k, int slot) {
    const unsigned char* src = wimg + (size_t)k * 16384 + (size_t)t * 16;
    __builtin_amdgcn_global_load_lds(
        (const __attribute__((address_space(1))) void*)src,
        (__attribute__((address_space(3))) void*)(&ldsB[slot][t * 16]), 16, 0, 0);
    __builtin_amdgcn_global_load_lds(
        (const __attribute__((address_space(1))) void*)(src + 8192),
        (__attribute__((address_space(3))) void*)(&ldsB[slot][t * 16 + 8192]), 16, 0, 0);
  };

  const unsigned bb = (unsigned)(cg * 8192 + lane * 16);

  // one tap, no syncs inside: A(kn+2) gathers + idx(kn+4) + 16 MFMAs
  auto do_tap = [&](int kn, int slot,
                    bf16x8& A0, bf16x8& A1, bf16x8& A2, bf16x8& A3,
                    int& Q0, int& Q1, bool doG) {
    const unsigned char* bufR = ldsB[slot];
    bf16x8 nA0, nA1, nA2, nA3;
    if (doG) {
      const unsigned char* p0 = gp(Q0, ok0);
      const unsigned char* p1 = gp(Q1, ok1);
      nA0 = *(const bf16x8*)p0; nA1 = *(const bf16x8*)(p0 + 64);
      nA2 = *(const bf16x8*)p1; nA3 = *(const bf16x8*)(p1 + 64);
    }
    int kq = (kn + 4 < KTAP) ? (kn + 4) : (KTAP - 1);
    int nQ0 = nmap[(size_t)kq * NPTS + nc0];
    int nQ1 = nmap[(size_t)kq * NPTS + nc1];
    #pragma unroll
    for (int kk = 0; kk < 2; ++kk) {
      bf16x8 b0 = *(const bf16x8*)(bufR + bb + kk * 1024 + 0 * 2048);
      bf16x8 b1 = *(const bf16x8*)(bufR + bb + kk * 1024 + 1 * 2048);
      bf16x8 b2 = *(const bf16x8*)(bufR + bb + kk * 1024 + 2 * 2048);
      bf16x8 b3 = *(const bf16x8*)(bufR + bb + kk * 1024 + 3 * 2048);
      bf16x8 a0 = kk ? A1 : A0;
      bf16x8 a1 = kk ? A3 : A2;
      acc[0][0] = __builtin_amdgcn_mfma_f32_16x16x32_bf16(a0, b0, acc[0][0], 0, 0, 0);
      acc[0][1] = __builtin_amdgcn_mfma_f32_16x16x32_bf16(a0, b1, acc[0][1], 0, 0, 0);
      acc[0][2] = __builtin_amdgcn_mfma_f32_16x16x32_bf16(a0, b2, acc[0][2], 0, 0, 0);
      acc[0][3] = __builtin_amdgcn_mfma_f32_16x16x32_bf16(a0, b3, acc[0][3], 0, 0, 0);
      acc[1][0] = __builtin_amdgcn_mfma_f32_16x16x32_bf16(a1, b0, acc[1][0], 0, 0, 0);
      acc[1][1] = __builtin_amdgcn_mfma_f32_16x16x32_bf16(a1, b1, acc[1][1], 0, 0, 0);
      acc[1][2] = __builtin_amdgcn_mfma_f32_16x16x32_bf16(a1, b2, acc[1][2], 0, 0, 0);
      acc[1][3] = __builtin_amdgcn_mfma_f32_16x16x32_bf16(a1, b3, acc[1][3], 0, 0, 0);
    }
    if (doG) { A0 = nA0; A1 = nA1; A2 = nA2; A3 = nA3; }
    Q0 = nQ0; Q1 = nQ1;
  };

  // ---- prologue: idx taps 0..3; A(0), A(1); stage tap 0 ----
  int j00 = nmap[nc0],                     j01 = nmap[nc1];
  int j10 = nmap[(size_t)NPTS + nc0],      j11 = nmap[(size_t)NPTS + nc1];
  int q00 = nmap[(size_t)2 * NPTS + nc0],  q01 = nmap[(size_t)2 * NPTS + nc1];
  int q10 = nmap[(size_t)3 * NPTS + nc0],  q11 = nmap[(size_t)3 * NPTS + nc1];

  bf16x8 aC0, aC1, aC2, aC3;   // even taps
  bf16x8 aN0, aN1, aN2, aN3;   // odd taps
  { const unsigned char* p = gp(j00, ok0); aC0 = *(const bf16x8*)p; aC1 = *(const bf16x8*)(p + 64); }
  { const unsigned char* p = gp(j01, ok1); aC2 = *(const bf16x8*)p; aC3 = *(const bf16x8*)(p + 64); }
  { const unsigned char* p = gp(j10, ok0); aN0 = *(const bf16x8*)p; aN1 = *(const bf16x8*)(p + 64); }
  { const unsigned char* p = gp(j11, ok1); aN2 = *(const bf16x8*)p; aN3 = *(const bf16x8*)(p + 64); }

  stage(0, 0);
  __syncthreads();   // tap-0 B staged (full drain; correct by construction)

  // ---- main loop: 1 barrier per tap; stage(kn+1) issued before compute ----
  #pragma unroll 1
  for (int kn = 0; kn < KTAP - 1; kn += 2) {
    stage(kn + 1, 1);
    do_tap(kn, 0, aC0, aC1, aC2, aC3, q00, q01, true);
    __syncthreads();                      // glds(kn+1) done; readers done slot0
    if (kn + 2 < KTAP) stage(kn + 2, 0);
    do_tap(kn + 1, 1, aN0, aN1, aN2, aN3, q10, q11, true);
    __syncthreads();                      // glds(kn+2) done; readers done slot1
  }
  do_tap(KTAP - 1, 0, aC0, aC1, aC2, aC3, q00, q01, false);   // tap 26 (even)

  // ---- epilogue: guarded stores + wave-reduced sums -> 32-shadow atomics ----
  float* mysh = shadow + (blockIdx.x & (NSHADOW - 1)) * 256;
  #pragma unroll
  for (int nf = 0; nf < 4; ++nf) {
    int c = cg * 64 + nf * 16 + l15;
    float s = 0.f, s2 = 0.f;
    #pragma unroll
    for (int rt = 0; rt < 2; ++rt) {
      #pragma unroll
      for (int r = 0; r < 4; ++r) {
        float v = acc[rt][nf][r];
        int n = n0 + rg * 32 + rt * 16 + lg * 4 + r;
        if (n < NPTS) {
          s += v; s2 += v * v;
          out[(size_t)n * OUTC + c] = v;
        }
      }
    }
    s  += __shfl_xor(s, 16);  s  += __shfl_xor(s, 32);
    s2 += __shfl_xor(s2, 16); s2 += __shfl_xor(s2, 32);
    if (lane < 16) {
      atomicAdd(&mysh[c], s);
      atomicAdd(&mysh[128 + c], s2);
    }
  }
}

__global__ void finalize_stats(const float* __restrict__ shadow,
                               const float* __restrict__ gamma,
                               const float* __restrict__ beta,
                               float* __restrict__ scale,
                               float* __restrict__ shift) {
  __shared__ float accs[256];
  int t = threadIdx.x;
  float s = 0.f;
  for (int b = 0; b < NSHADOW; ++b) s += shadow[b * 256 + t];
  accs[t] = s;
  __syncthreads();
  if (t < OUTC) {
    float mean = accs[t] * (1.0f / (float)NPTS);
    float var  = accs[128 + t] * (1.0f / (float)NPTS) - mean * mean;
    var = fmaxf(var, 0.f);
    float sc = gamma[t] * rsqrtf(var + EPSV);
    scale[t] = sc;
    shift[t] = beta[t] - mean * sc;
  }
}

__global__ __launch_bounds__(256) void norm_relu(float* __restrict__ out,
                                                 const float* __restrict__ scale,
                                                 const float* __restrict__ shift) {
  __shared__ float s_sc[OUTC], s_sh[OUTC];
  if (threadIdx.x < OUTC) {
    s_sc[threadIdx.x] = scale[threadIdx.x];
    s_sh[threadIdx.x] = shift[threadIdx.x];
  }
  __syncthreads();
  const long total = (long)NPTS * OUTC / 4;
  for (long i = (long)blockIdx.x * blockDim.x + threadIdx.x; i < total;
       i += (long)gridDim.x * blockDim.x) {
    float4 v = ((float4*)out)[i];
    int cb = (int)(i & 31) * 4;
    v.x = fmaxf(v.x * s_sc[cb + 0] + s_sh[cb + 0], 0.f);
    v.y = fmaxf(v.y * s_sc[cb + 1] + s_sh[cb + 1], 0.f);
    v.z = fmaxf(v.z * s_sc[cb + 2] + s_sh[cb + 2], 0.f);
    v.w = fmaxf(v.w * s_sc[cb + 3] + s_sh[cb + 3], 0.f);
    ((float4*)out)[i] = v;
  }
}

extern "C" void kernel_launch(void* const* d_in, const int* in_sizes, int n_in,
                              void* d_out, int out_size, void* d_ws, size_t ws_size,
                              hipStream_t stream) {
  (void)in_sizes; (void)n_in; (void)out_size; (void)ws_size;
  const float* feats  = (const float*)d_in[0];
  const float* weight = (const float*)d_in[1];
  const float* gamma  = (const float*)d_in[2];
  const float* beta   = (const float*)d_in[3];
  const int*   nmap   = (const int*)d_in[4];
  float* out = (float*)d_out;

  unsigned char* ws = (unsigned char*)d_ws;
  const size_t FBF_BYTES  = (size_t)(NPTS + 1) * 128;  // 25,600,128 (+ zero row)
  const size_t WIMG_BYTES = (size_t)KTAP * 16384;      // 442,368
  unsigned short* fbf = (unsigned short*)ws;
  unsigned char* wimg = ws + FBF_BYTES;
  float* shadow = (float*)(ws + FBF_BYTES + WIMG_BYTES);  // 32*256
  float* scale  = shadow + NSHADOW * 256;
  float* shift  = scale + 128;

  hipMemsetAsync(shadow, 0, NSHADOW * 256 * sizeof(float), stream);
  hipMemsetAsync(fbf + (size_t)NPTS * 64, 0, 128, stream);   // zero row
  prep_wfrag<<<KTAP, 256, 0, stream>>>(weight, wimg);
  prep_feats<<<6250, 256, 0, stream>>>(feats, fbf);
  int grid = (NPTS + BM - 1) / BM;  // 1563
  conv_main<<<grid, 512, 0, stream>>>(fbf, nmap, wimg, out, shadow);
  finalize_stats<<<1, 256, 0, stream>>>(shadow, gamma, beta, scale, shift);
  norm_relu<<<4096, 256, 0, stream>>>(out, scale, shift);
}

// Round 17
// 169.053 us; speedup vs baseline: 5.0622x; 1.0837x over previous
//
#include <hip/hip_runtime.h>
#include <hip/hip_bf16.h>

#define NPTS 200000
#define INC  64
#define OUTC 128
#define KTAP 27
#define EPSV 1e-5f
#define BM   128
#define NSHADOW 32

typedef __attribute__((ext_vector_type(8))) short bf16x8;
typedef __attribute__((ext_vector_type(4))) float f32x4;

__device__ __forceinline__ unsigned short f2bf(float f) {
  unsigned int u = __float_as_uint(f);
  return (unsigned short)((u + 0x7FFFu + ((u >> 16) & 1u)) >> 16);
}

// Fragment-packed bf16 weight image, 16KB/tap (R9-verified layout):
// chunk id=(ct*2+kk)*64+lane holds w[kk*32+(lane>>4)*8+j][ct*16+(lane&15)], j=0..7
__global__ void prep_wfrag(const float* __restrict__ w, unsigned char* __restrict__ img) {
  int tap = blockIdx.x;
  const float* wk = w + tap * (INC * OUTC);
  for (int id = threadIdx.x; id < 1024; id += blockDim.x) {
    int lane = id & 63;
    int ck   = id >> 6;
    int ct   = ck >> 1, kk = ck & 1;
    int c    = ct * 16 + (lane & 15);
    int k0   = kk * 32 + (lane >> 4) * 8;
    ushort4 lo, hi;
    lo.x = f2bf(wk[(k0+0)*OUTC + c]); lo.y = f2bf(wk[(k0+1)*OUTC + c]);
    lo.z = f2bf(wk[(k0+2)*OUTC + c]); lo.w = f2bf(wk[(k0+3)*OUTC + c]);
    hi.x = f2bf(wk[(k0+4)*OUTC + c]); hi.y = f2bf(wk[(k0+5)*OUTC + c]);
    hi.z = f2bf(wk[(k0+6)*OUTC + c]); hi.w = f2bf(wk[(k0+7)*OUTC + c]);
    unsigned char* d = img + (size_t)tap * 16384 + (size_t)id * 16;
    *(ushort4*)d       = lo;
    *(ushort4*)(d + 8) = hi;
  }
}

// feats fp32 (N x 64) -> bf16 rows of 128B.
__global__ __launch_bounds__(256) void prep_feats(const float* __restrict__ f,
                                                  unsigned short* __restrict__ o) {
  size_t i = (size_t)blockIdx.x * 256 + threadIdx.x;
  float4 a = ((const float4*)f)[i * 2];
  float4 b = ((const float4*)f)[i * 2 + 1];
  ushort4 ha = make_ushort4(f2bf(a.x), f2bf(a.y), f2bf(a.z), f2bf(a.w));
  ushort4 hb = make_ushort4(f2bf(b.x), f2bf(b.y), f2bf(b.z), f2bf(b.w));
  ((ushort4*)o)[i * 2]     = ha;
  ((ushort4*)o)[i * 2 + 1] = hb;
}

__global__ __launch_bounds__(512, 4) void conv_main(
    const unsigned short* __restrict__ fbf,   // NPTS+1 rows; row NPTS is zeros
    const int*   __restrict__ nmap,
    const unsigned char* __restrict__ wimg,
    float* __restrict__ out,
    float* __restrict__ shadow)
{
  __shared__ __align__(16) unsigned char ldsB[2][16384];   // 32KB

  const int t    = threadIdx.x;
  const int lane = t & 63;
  const int w    = t >> 6;       // 0..7
  const int cg   = w & 1;        // col group (64 cols)
  const int rg   = w >> 1;       // row group (32 rows, wave-exclusive)
  const int n0   = blockIdx.x * BM;
  const int l15  = lane & 15;
  const int lg   = lane >> 4;

  f32x4 zv = {0.f, 0.f, 0.f, 0.f};
  f32x4 acc[2][4];
  #pragma unroll
  for (int i = 0; i < 2; ++i)
    #pragma unroll
    for (int j = 0; j < 4; ++j) acc[i][j] = zv;

  const int nr0 = n0 + rg * 32 + l15;
  const int nr1 = nr0 + 16;
  const bool ok0 = nr0 < NPTS, ok1 = nr1 < NPTS;
  const int nc0 = ok0 ? nr0 : (NPTS - 1);
  const int nc1 = ok1 ? nr1 : (NPTS - 1);

  const unsigned char* fbp = (const unsigned char*)fbf;
  // invalid (g<0) or tail row -> zero row NPTS: no masking anywhere
  auto gp = [&](int g, bool ok) -> const unsigned char* {
    int gc = (g >= 0) ? g : NPTS;
    gc = ok ? gc : NPTS;
    return fbp + (size_t)gc * 128 + lg * 16;
  };

  // stage tap k into slot (16KB linear glds copy) — 2 VMEM ops
  auto stage = [&](int k, int slot) {
    const unsigned char* src = wimg + (size_t)k * 16384 + (size_t)t * 16;
    __builtin_amdgcn_global_load_lds(
        (const __attribute__((address_space(1))) void*)src,
        (__attribute__((address_space(3))) void*)(&ldsB[slot][t * 16]), 16, 0, 0);
    __builtin_amdgcn_global_load_lds(
        (const __attribute__((address_space(1))) void*)(src + 8192),
        (__attribute__((address_space(3))) void*)(&ldsB[slot][t * 16 + 8192]), 16, 0, 0);
  };

  const unsigned bb = (unsigned)(cg * 8192 + lane * 16);

  auto compute = [&](int slot, bf16x8& A0, bf16x8& A1, bf16x8& A2, bf16x8& A3) {
    const unsigned char* bufR = ldsB[slot];
    #pragma unroll
    for (int kk = 0; kk < 2; ++kk) {
      bf16x8 b0 = *(const bf16x8*)(bufR + bb + kk * 1024 + 0 * 2048);
      bf16x8 b1 = *(const bf16x8*)(bufR + bb + kk * 1024 + 1 * 2048);
      bf16x8 b2 = *(const bf16x8*)(bufR + bb + kk * 1024 + 2 * 2048);
      bf16x8 b3 = *(const bf16x8*)(bufR + bb + kk * 1024 + 3 * 2048);
      bf16x8 a0 = kk ? A1 : A0;
      bf16x8 a1 = kk ? A3 : A2;
      acc[0][0] = __builtin_amdgcn_mfma_f32_16x16x32_bf16(a0, b0, acc[0][0], 0, 0, 0);
      acc[0][1] = __builtin_amdgcn_mfma_f32_16x16x32_bf16(a0, b1, acc[0][1], 0, 0, 0);
      acc[0][2] = __builtin_amdgcn_mfma_f32_16x16x32_bf16(a0, b2, acc[0][2], 0, 0, 0);
      acc[0][3] = __builtin_amdgcn_mfma_f32_16x16x32_bf16(a0, b3, acc[0][3], 0, 0, 0);
      acc[1][0] = __builtin_amdgcn_mfma_f32_16x16x32_bf16(a1, b0, acc[1][0], 0, 0, 0);
      acc[1][1] = __builtin_amdgcn_mfma_f32_16x16x32_bf16(a1, b1, acc[1][1], 0, 0, 0);
      acc[1][2] = __builtin_amdgcn_mfma_f32_16x16x32_bf16(a1, b2, acc[1][2], 0, 0, 0);
      acc[1][3] = __builtin_amdgcn_mfma_f32_16x16x32_bf16(a1, b3, acc[1][3], 0, 0, 0);
    }
  };

  // One tap with UNIFORM 8-VMEM ledger: [2 glds][4 gathers][2 nmap], order
  // pinned by sched_barrier. End-of-tap: vmcnt(6) retires this tap's glds
  // (+ all older ops); this tap's gathers+nmap (6 newest) stay in flight
  // across the raw barrier. Dummy (clamped) issues at the tail keep the
  // count uniform — R10's tail-guard bug corrected.
  auto do_tap = [&](int kn, int slot,
                    bf16x8& A0, bf16x8& A1, bf16x8& A2, bf16x8& A3,
                    int& Q0, int& Q1) {
    // [1] glds B(kn+1) -> other slot (clamped at tail; writes non-read slot)
    int knx = (kn + 1 < KTAP) ? (kn + 1) : (KTAP - 1);
    stage(knx, slot ^ 1);
    __builtin_amdgcn_sched_barrier(0);
    // [2] A(kn+2) gathers (unconditional; Q holds clamped idx) + nmap(kn+4)
    const unsigned char* p0 = gp(Q0, ok0);
    const unsigned char* p1 = gp(Q1, ok1);
    bf16x8 nA0 = *(const bf16x8*)p0;
    bf16x8 nA1 = *(const bf16x8*)(p0 + 64);
    bf16x8 nA2 = *(const bf16x8*)p1;
    bf16x8 nA3 = *(const bf16x8*)(p1 + 64);
    int kq = (kn + 4 < KTAP) ? (kn + 4) : (KTAP - 1);
    int nQ0 = nmap[(size_t)kq * NPTS + nc0];
    int nQ1 = nmap[(size_t)kq * NPTS + nc1];
    __builtin_amdgcn_sched_barrier(0);
    // [3] compute tap kn
    compute(slot, A0, A1, A2, A3);
    // [4] rotate (temps -> WAR-safe at tail; garbage after tap 25/26 unused)
    A0 = nA0; A1 = nA1; A2 = nA2; A3 = nA3;
    Q0 = nQ0; Q1 = nQ1;
    // [5] counted sync — gathers survive the barrier
    asm volatile("s_waitcnt vmcnt(6)" ::: "memory");
    asm volatile("s_waitcnt lgkmcnt(0)" ::: "memory");
    __builtin_amdgcn_s_barrier();
    __builtin_amdgcn_sched_barrier(0);
  };

  // ---- prologue: idx taps 0..3; A(0), A(1); stage tap 0; ONE full drain ----
  int j00 = nmap[nc0],                     j01 = nmap[nc1];
  int j10 = nmap[(size_t)NPTS + nc0],      j11 = nmap[(size_t)NPTS + nc1];
  int q00 = nmap[(size_t)2 * NPTS + nc0],  q01 = nmap[(size_t)2 * NPTS + nc1];
  int q10 = nmap[(size_t)3 * NPTS + nc0],  q11 = nmap[(size_t)3 * NPTS + nc1];

  bf16x8 aC0, aC1, aC2, aC3;   // even taps
  bf16x8 aN0, aN1, aN2, aN3;   // odd taps
  { const unsigned char* p = gp(j00, ok0); aC0 = *(const bf16x8*)p; aC1 = *(const bf16x8*)(p + 64); }
  { const unsigned char* p = gp(j01, ok1); aC2 = *(const bf16x8*)p; aC3 = *(const bf16x8*)(p + 64); }
  { const unsigned char* p = gp(j10, ok0); aN0 = *(const bf16x8*)p; aN1 = *(const bf16x8*)(p + 64); }
  { const unsigned char* p = gp(j11, ok1); aN2 = *(const bf16x8*)p; aN3 = *(const bf16x8*)(p + 64); }

  stage(0, 0);
  asm volatile("s_waitcnt vmcnt(0)" ::: "memory");
  asm volatile("s_waitcnt lgkmcnt(0)" ::: "memory");
  __builtin_amdgcn_s_barrier();
  __builtin_amdgcn_sched_barrier(0);

  // ---- main loop: taps 0..25 with counted-vmcnt raw barriers ----
  #pragma unroll 1
  for (int kn = 0; kn < KTAP - 1; kn += 2) {
    do_tap(kn,     0, aC0, aC1, aC2, aC3, q00, q01);
    do_tap(kn + 1, 1, aN0, aN1, aN2, aN3, q10, q11);
  }
  // ---- tap 26: after the last barrier; no ledger needed ----
  compute(0, aC0, aC1, aC2, aC3);

  // ---- epilogue: guarded stores + wave-reduced sums -> 32-shadow atomics ----
  float* mysh = shadow + (blockIdx.x & (NSHADOW - 1)) * 256;
  #pragma unroll
  for (int nf = 0; nf < 4; ++nf) {
    int c = cg * 64 + nf * 16 + l15;
    float s = 0.f, s2 = 0.f;
    #pragma unroll
    for (int rt = 0; rt < 2; ++rt) {
      #pragma unroll
      for (int r = 0; r < 4; ++r) {
        float v = acc[rt][nf][r];
        int n = n0 + rg * 32 + rt * 16 + lg * 4 + r;
        if (n < NPTS) {
          s += v; s2 += v * v;
          out[(size_t)n * OUTC + c] = v;
        }
      }
    }
    s  += __shfl_xor(s, 16);  s  += __shfl_xor(s, 32);
    s2 += __shfl_xor(s2, 16); s2 += __shfl_xor(s2, 32);
    if (lane < 16) {
      atomicAdd(&mysh[c], s);
      atomicAdd(&mysh[128 + c], s2);
    }
  }
}

__global__ void finalize_stats(const float* __restrict__ shadow,
                               const float* __restrict__ gamma,
                               const float* __restrict__ beta,
                               float* __restrict__ scale,
                               float* __restrict__ shift) {
  __shared__ float accs[256];
  int t = threadIdx.x;
  float s = 0.f;
  for (int b = 0; b < NSHADOW; ++b) s += shadow[b * 256 + t];
  accs[t] = s;
  __syncthreads();
  if (t < OUTC) {
    float mean = accs[t] * (1.0f / (float)NPTS);
    float var  = accs[128 + t] * (1.0f / (float)NPTS) - mean * mean;
    var = fmaxf(var, 0.f);
    float sc = gamma[t] * rsqrtf(var + EPSV);
    scale[t] = sc;
    shift[t] = beta[t] - mean * sc;
  }
}

__global__ __launch_bounds__(256) void norm_relu(float* __restrict__ out,
                                                 const float* __restrict__ scale,
                                                 const float* __restrict__ shift) {
  __shared__ float s_sc[OUTC], s_sh[OUTC];
  if (threadIdx.x < OUTC) {
    s_sc[threadIdx.x] = scale[threadIdx.x];
    s_sh[threadIdx.x] = shift[threadIdx.x];
  }
  __syncthreads();
  const long total = (long)NPTS * OUTC / 4;
  for (long i = (long)blockIdx.x * blockDim.x + threadIdx.x; i < total;
       i += (long)gridDim.x * blockDim.x) {
    float4 v = ((float4*)out)[i];
    int cb = (int)(i & 31) * 4;
    v.x = fmaxf(v.x * s_sc[cb + 0] + s_sh[cb + 0], 0.f);
    v.y = fmaxf(v.y * s_sc[cb + 1] + s_sh[cb + 1], 0.f);
    v.z = fmaxf(v.z * s_sc[cb + 2] + s_sh[cb + 2], 0.f);
    v.w = fmaxf(v.w * s_sc[cb + 3] + s_sh[cb + 3], 0.f);
    ((float4*)out)[i] = v;
  }
}

extern "C" void kernel_launch(void* const* d_in, const int* in_sizes, int n_in,
                              void* d_out, int out_size, void* d_ws, size_t ws_size,
                              hipStream_t stream) {
  (void)in_sizes; (void)n_in; (void)out_size; (void)ws_size;
  const float* feats  = (const float*)d_in[0];
  const float* weight = (const float*)d_in[1];
  const float* gamma  = (const float*)d_in[2];
  const float* beta   = (const float*)d_in[3];
  const int*   nmap   = (const int*)d_in[4];
  float* out = (float*)d_out;

  unsigned char* ws = (unsigned char*)d_ws;
  const size_t FBF_BYTES  = (size_t)(NPTS + 1) * 128;  // 25,600,128 (+ zero row)
  const size_t WIMG_BYTES = (size_t)KTAP * 16384;      // 442,368
  unsigned short* fbf = (unsigned short*)ws;
  unsigned char* wimg = ws + FBF_BYTES;
  float* shadow = (float*)(ws + FBF_BYTES + WIMG_BYTES);  // 32*256
  float* scale  = shadow + NSHADOW * 256;
  float* shift  = scale + 128;

  hipMemsetAsync(shadow, 0, NSHADOW * 256 * sizeof(float), stream);
  hipMemsetAsync(fbf + (size_t)NPTS * 64, 0, 128, stream);   // zero row
  prep_wfrag<<<KTAP, 256, 0, stream>>>(weight, wimg);
  prep_feats<<<6250, 256, 0, stream>>>(feats, fbf);
  int grid = (NPTS + BM - 1) / BM;  // 1563
  conv_main<<<grid, 512, 0, stream>>>(fbf, nmap, wimg, out, shadow);
  finalize_stats<<<1, 256, 0, stream>>>(shadow, gamma, beta, scale, shift);
  norm_relu<<<4096, 256, 0, stream>>>(out, scale, shift);
}

// Round 18
// 167.039 us; speedup vs baseline: 5.1232x; 1.0121x over previous
//
#include <hip/hip_runtime.h>
#include <hip/hip_bf16.h>

#define NPTS 200000
#define INC  64
#define OUTC 128
#define KTAP 27
#define EPSV 1e-5f
#define BM   128
#define NSHADOW 32

typedef __attribute__((ext_vector_type(8))) short bf16x8;
typedef __attribute__((ext_vector_type(4))) float f32x4;

__device__ __forceinline__ unsigned short f2bf(float f) {
  unsigned int u = __float_as_uint(f);
  return (unsigned short)((u + 0x7FFFu + ((u >> 16) & 1u)) >> 16);
}

// Fragment-packed bf16 weight image, 16KB/tap (R9-verified layout):
// chunk id=(ct*2+kk)*64+lane holds w[kk*32+(lane>>4)*8+j][ct*16+(lane&15)], j=0..7
__global__ void prep_wfrag(const float* __restrict__ w, unsigned char* __restrict__ img) {
  int tap = blockIdx.x;
  const float* wk = w + tap * (INC * OUTC);
  for (int id = threadIdx.x; id < 1024; id += blockDim.x) {
    int lane = id & 63;
    int ck   = id >> 6;
    int ct   = ck >> 1, kk = ck & 1;
    int c    = ct * 16 + (lane & 15);
    int k0   = kk * 32 + (lane >> 4) * 8;
    ushort4 lo, hi;
    lo.x = f2bf(wk[(k0+0)*OUTC + c]); lo.y = f2bf(wk[(k0+1)*OUTC + c]);
    lo.z = f2bf(wk[(k0+2)*OUTC + c]); lo.w = f2bf(wk[(k0+3)*OUTC + c]);
    hi.x = f2bf(wk[(k0+4)*OUTC + c]); hi.y = f2bf(wk[(k0+5)*OUTC + c]);
    hi.z = f2bf(wk[(k0+6)*OUTC + c]); hi.w = f2bf(wk[(k0+7)*OUTC + c]);
    unsigned char* d = img + (size_t)tap * 16384 + (size_t)id * 16;
    *(ushort4*)d       = lo;
    *(ushort4*)(d + 8) = hi;
  }
}

// feats fp32 (N x 64) -> bf16 rows of 128B.
__global__ __launch_bounds__(256) void prep_feats(const float* __restrict__ f,
                                                  unsigned short* __restrict__ o) {
  size_t i = (size_t)blockIdx.x * 256 + threadIdx.x;
  float4 a = ((const float4*)f)[i * 2];
  float4 b = ((const float4*)f)[i * 2 + 1];
  ushort4 ha = make_ushort4(f2bf(a.x), f2bf(a.y), f2bf(a.z), f2bf(a.w));
  ushort4 hb = make_ushort4(f2bf(b.x), f2bf(b.y), f2bf(b.z), f2bf(b.w));
  ((ushort4*)o)[i * 2]     = ha;
  ((ushort4*)o)[i * 2 + 1] = hb;
}

__global__ __launch_bounds__(512, 4) void conv_main(
    const unsigned short* __restrict__ fbf,   // NPTS+1 rows; row NPTS is zeros
    const int*   __restrict__ nmap,
    const unsigned char* __restrict__ wimg,
    float* __restrict__ out,
    float* __restrict__ shadow)
{
  __shared__ __align__(16) unsigned char ldsB[4][16384];   // 64KB, 2 slot-pairs

  const int t    = threadIdx.x;
  const int lane = t & 63;
  const int w    = t >> 6;       // 0..7
  const int cg   = w & 1;        // col group (64 cols)
  const int rg   = w >> 1;       // row group (32 rows, wave-exclusive)
  const int n0   = blockIdx.x * BM;
  const int l15  = lane & 15;
  const int lg   = lane >> 4;

  f32x4 zv = {0.f, 0.f, 0.f, 0.f};
  f32x4 acc[2][4];
  #pragma unroll
  for (int i = 0; i < 2; ++i)
    #pragma unroll
    for (int j = 0; j < 4; ++j) acc[i][j] = zv;

  const int nr0 = n0 + rg * 32 + l15;
  const int nr1 = nr0 + 16;
  const bool ok0 = nr0 < NPTS, ok1 = nr1 < NPTS;
  const int nc0 = ok0 ? nr0 : (NPTS - 1);
  const int nc1 = ok1 ? nr1 : (NPTS - 1);

  const unsigned char* fbp = (const unsigned char*)fbf;
  // invalid (g<0) or tail row -> zero row NPTS: no masking anywhere
  auto gp = [&](int g, bool ok) -> const unsigned char* {
    int gc = (g >= 0) ? g : NPTS;
    gc = ok ? gc : NPTS;
    return fbp + (size_t)gc * 128 + lg * 16;
  };

  // stage tap k into slot (16KB linear glds copy) — 2 VMEM ops
  auto stage = [&](int k, int slot) {
    const unsigned char* src = wimg + (size_t)k * 16384 + (size_t)t * 16;
    __builtin_amdgcn_global_load_lds(
        (const __attribute__((address_space(1))) void*)src,
        (__attribute__((address_space(3))) void*)(&ldsB[slot][t * 16]), 16, 0, 0);
    __builtin_amdgcn_global_load_lds(
        (const __attribute__((address_space(1))) void*)(src + 8192),
        (__attribute__((address_space(3))) void*)(&ldsB[slot][t * 16 + 8192]), 16, 0, 0);
  };

  const unsigned bb = (unsigned)(cg * 8192 + lane * 16);

  auto compute = [&](int slot, bf16x8& A0, bf16x8& A1, bf16x8& A2, bf16x8& A3) {
    const unsigned char* bufR = ldsB[slot];
    #pragma unroll
    for (int kk = 0; kk < 2; ++kk) {
      bf16x8 b0 = *(const bf16x8*)(bufR + bb + kk * 1024 + 0 * 2048);
      bf16x8 b1 = *(const bf16x8*)(bufR + bb + kk * 1024 + 1 * 2048);
      bf16x8 b2 = *(const bf16x8*)(bufR + bb + kk * 1024 + 2 * 2048);
      bf16x8 b3 = *(const bf16x8*)(bufR + bb + kk * 1024 + 3 * 2048);
      bf16x8 a0 = kk ? A1 : A0;
      bf16x8 a1 = kk ? A3 : A2;
      acc[0][0] = __builtin_amdgcn_mfma_f32_16x16x32_bf16(a0, b0, acc[0][0], 0, 0, 0);
      acc[0][1] = __builtin_amdgcn_mfma_f32_16x16x32_bf16(a0, b1, acc[0][1], 0, 0, 0);
      acc[0][2] = __builtin_amdgcn_mfma_f32_16x16x32_bf16(a0, b2, acc[0][2], 0, 0, 0);
      acc[0][3] = __builtin_amdgcn_mfma_f32_16x16x32_bf16(a0, b3, acc[0][3], 0, 0, 0);
      acc[1][0] = __builtin_amdgcn_mfma_f32_16x16x32_bf16(a1, b0, acc[1][0], 0, 0, 0);
      acc[1][1] = __builtin_amdgcn_mfma_f32_16x16x32_bf16(a1, b1, acc[1][1], 0, 0, 0);
      acc[1][2] = __builtin_amdgcn_mfma_f32_16x16x32_bf16(a1, b2, acc[1][2], 0, 0, 0);
      acc[1][3] = __builtin_amdgcn_mfma_f32_16x16x32_bf16(a1, b3, acc[1][3], 0, 0, 0);
    }
  };

  // tap body, NO sync: [4 gathers + 2 nmap] (pinned) then compute + rotate.
  // Gathers target tap kn+2 (clamped idx lives in Q), nmap targets kn+4.
  auto tap_body = [&](int kn, int slot,
                      bf16x8& A0, bf16x8& A1, bf16x8& A2, bf16x8& A3,
                      int& Q0, int& Q1) {
    const unsigned char* p0 = gp(Q0, ok0);
    const unsigned char* p1 = gp(Q1, ok1);
    bf16x8 nA0 = *(const bf16x8*)p0;
    bf16x8 nA1 = *(const bf16x8*)(p0 + 64);
    bf16x8 nA2 = *(const bf16x8*)p1;
    bf16x8 nA3 = *(const bf16x8*)(p1 + 64);
    int kq = (kn + 4 < KTAP) ? (kn + 4) : (KTAP - 1);
    int nQ0 = nmap[(size_t)kq * NPTS + nc0];
    int nQ1 = nmap[(size_t)kq * NPTS + nc1];
    __builtin_amdgcn_sched_barrier(0);
    compute(slot, A0, A1, A2, A3);
    A0 = nA0; A1 = nA1; A2 = nA2; A3 = nA3;
    Q0 = nQ0; Q1 = nQ1;
  };

  // ---- prologue: idx taps 0..3; A(0), A(1); stage taps 0,1; ONE full drain ----
  int j00 = nmap[nc0],                     j01 = nmap[nc1];
  int j10 = nmap[(size_t)NPTS + nc0],      j11 = nmap[(size_t)NPTS + nc1];
  int q00 = nmap[(size_t)2 * NPTS + nc0],  q01 = nmap[(size_t)2 * NPTS + nc1];
  int q10 = nmap[(size_t)3 * NPTS + nc0],  q11 = nmap[(size_t)3 * NPTS + nc1];

  bf16x8 aC0, aC1, aC2, aC3;   // even taps
  bf16x8 aN0, aN1, aN2, aN3;   // odd taps
  { const unsigned char* p = gp(j00, ok0); aC0 = *(const bf16x8*)p; aC1 = *(const bf16x8*)(p + 64); }
  { const unsigned char* p = gp(j01, ok1); aC2 = *(const bf16x8*)p; aC3 = *(const bf16x8*)(p + 64); }
  { const unsigned char* p = gp(j10, ok0); aN0 = *(const bf16x8*)p; aN1 = *(const bf16x8*)(p + 64); }
  { const unsigned char* p = gp(j11, ok1); aN2 = *(const bf16x8*)p; aN3 = *(const bf16x8*)(p + 64); }

  stage(0, 0);
  stage(1, 1);
  asm volatile("s_waitcnt vmcnt(0)" ::: "memory");
  asm volatile("s_waitcnt lgkmcnt(0)" ::: "memory");
  __builtin_amdgcn_s_barrier();
  __builtin_amdgcn_sched_barrier(0);

  // ---- main loop: 13 groups of 2 taps; ONE rendezvous per group ----
  // Group g: reads slot-pair (g&1), stages pair (g&1)^1 with taps 2g+2,2g+3.
  // Ledger/group: [4 glds][4 gath][2 nmap][4 gath][2 nmap] = 16 VMEM;
  // vmcnt(12) at group end retires exactly the glds; 12 newest stay in flight.
  #pragma unroll 1
  for (int g = 0; g < 13; ++g) {
    const int kn = 2 * g;
    const int p  = g & 1;
    const int q  = p ^ 1;
    int s0 = (kn + 2 < KTAP) ? (kn + 2) : (KTAP - 1);
    int s1 = (kn + 3 < KTAP) ? (kn + 3) : (KTAP - 1);
    stage(s0, q * 2 + 0);
    stage(s1, q * 2 + 1);
    __builtin_amdgcn_sched_barrier(0);
    tap_body(kn,     p * 2 + 0, aC0, aC1, aC2, aC3, q00, q01);
    tap_body(kn + 1, p * 2 + 1, aN0, aN1, aN2, aN3, q10, q11);
    asm volatile("s_waitcnt vmcnt(12)" ::: "memory");
    asm volatile("s_waitcnt lgkmcnt(0)" ::: "memory");
    __builtin_amdgcn_s_barrier();
    __builtin_amdgcn_sched_barrier(0);
  }
  // ---- tap 26: pair 1, slot 2 (staged by g=12, retired by its vmcnt(12)) ----
  compute(2, aC0, aC1, aC2, aC3);

  // ---- epilogue: guarded stores + wave-reduced sums -> 32-shadow atomics ----
  float* mysh = shadow + (blockIdx.x & (NSHADOW - 1)) * 256;
  #pragma unroll
  for (int nf = 0; nf < 4; ++nf) {
    int c = cg * 64 + nf * 16 + l15;
    float s = 0.f, s2 = 0.f;
    #pragma unroll
    for (int rt = 0; rt < 2; ++rt) {
      #pragma unroll
      for (int r = 0; r < 4; ++r) {
        float v = acc[rt][nf][r];
        int n = n0 + rg * 32 + rt * 16 + lg * 4 + r;
        if (n < NPTS) {
          s += v; s2 += v * v;
          out[(size_t)n * OUTC + c] = v;
        }
      }
    }
    s  += __shfl_xor(s, 16);  s  += __shfl_xor(s, 32);
    s2 += __shfl_xor(s2, 16); s2 += __shfl_xor(s2, 32);
    if (lane < 16) {
      atomicAdd(&mysh[c], s);
      atomicAdd(&mysh[128 + c], s2);
    }
  }
}

__global__ void finalize_stats(const float* __restrict__ shadow,
                               const float* __restrict__ gamma,
                               const float* __restrict__ beta,
                               float* __restrict__ scale,
                               float* __restrict__ shift) {
  __shared__ float accs[256];
  int t = threadIdx.x;
  float s = 0.f;
  for (int b = 0; b < NSHADOW; ++b) s += shadow[b * 256 + t];
  accs[t] = s;
  __syncthreads();
  if (t < OUTC) {
    float mean = accs[t] * (1.0f / (float)NPTS);
    float var  = accs[128 + t] * (1.0f / (float)NPTS) - mean * mean;
    var = fmaxf(var, 0.f);
    float sc = gamma[t] * rsqrtf(var + EPSV);
    scale[t] = sc;
    shift[t] = beta[t] - mean * sc;
  }
}

__global__ __launch_bounds__(256) void norm_relu(float* __restrict__ out,
                                                 const float* __restrict__ scale,
                                                 const float* __restrict__ shift) {
  __shared__ float s_sc[OUTC], s_sh[OUTC];
  if (threadIdx.x < OUTC) {
    s_sc[threadIdx.x] = scale[threadIdx.x];
    s_sh[threadIdx.x] = shift[threadIdx.x];
  }
  __syncthreads();
  const long total = (long)NPTS * OUTC / 4;
  for (long i = (long)blockIdx.x * blockDim.x + threadIdx.x; i < total;
       i += (long)gridDim.x * blockDim.x) {
    float4 v = ((float4*)out)[i];
    int cb = (int)(i & 31) * 4;
    v.x = fmaxf(v.x * s_sc[cb + 0] + s_sh[cb + 0], 0.f);
    v.y = fmaxf(v.y * s_sc[cb + 1] + s_sh[cb + 1], 0.f);
    v.z = fmaxf(v.z * s_sc[cb + 2] + s_sh[cb + 2], 0.f);
    v.w = fmaxf(v.w * s_sc[cb + 3] + s_sh[cb + 3], 0.f);
    ((float4*)out)[i] = v;
  }
}

extern "C" void kernel_launch(void* const* d_in, const int* in_sizes, int n_in,
                              void* d_out, int out_size, void* d_ws, size_t ws_size,
                              hipStream_t stream) {
  (void)in_sizes; (void)n_in; (void)out_size; (void)ws_size;
  const float* feats  = (const float*)d_in[0];
  const float* weight = (const float*)d_in[1];
  const float* gamma  = (const float*)d_in[2];
  const float* beta   = (const float*)d_in[3];
  const int*   nmap   = (const int*)d_in[4];
  float* out = (float*)d_out;

  unsigned char* ws = (unsigned char*)d_ws;
  const size_t FBF_BYTES  = (size_t)(NPTS + 1) * 128;  // 25,600,128 (+ zero row)
  const size_t WIMG_BYTES = (size_t)KTAP * 16384;      // 442,368
  unsigned short* fbf = (unsigned short*)ws;
  unsigned char* wimg = ws + FBF_BYTES;
  float* shadow = (float*)(ws + FBF_BYTES + WIMG_BYTES);  // 32*256
  float* scale  = shadow + NSHADOW * 256;
  float* shift  = scale + 128;

  hipMemsetAsync(shadow, 0, NSHADOW * 256 * sizeof(float), stream);
  hipMemsetAsync(fbf + (size_t)NPTS * 64, 0, 128, stream);   // zero row
  prep_wfrag<<<KTAP, 256, 0, stream>>>(weight, wimg);
  prep_feats<<<6250, 256, 0, stream>>>(feats, fbf);
  int grid = (NPTS + BM - 1) / BM;  // 1563
  conv_main<<<grid, 512, 0, stream>>>(fbf, nmap, wimg, out, shadow);
  finalize_stats<<<1, 256, 0, stream>>>(shadow, gamma, beta, scale, shift);
  norm_relu<<<4096, 256, 0, stream>>>(out, scale, shift);
}